// Round 9
// baseline (138.330 us; speedup 1.0000x reference)
//
#include <hip/hip_runtime.h>
#include <hip/hip_bf16.h>
#include <math.h>

#define NN 4096
#define FIN 512
#define HH 8
#define DD 64

typedef unsigned long long u64;
typedef unsigned int u32;
typedef float f32x4 __attribute__((ext_vector_type(4)));
typedef float f32x16 __attribute__((ext_vector_type(16)));
typedef short short8 __attribute__((ext_vector_type(8)));

#define GLOAD_LDS16(g, l)                                                              \
  __builtin_amdgcn_global_load_lds((const __attribute__((address_space(1))) u32*)(g),  \
                                   (__attribute__((address_space(3))) u32*)(l), 16, 0, 0)

#if __has_builtin(__builtin_amdgcn_exp2f)
#define EXP2F(x) __builtin_amdgcn_exp2f(x)
#else
#define EXP2F(x) exp2f(x)
#endif

__device__ inline ushort bf16rne(float f) {
    u32 u = __float_as_uint(f);
    u += 0x7FFFu + ((u >> 16) & 1u);
    return (ushort)(u >> 16);
}
__device__ inline float bf16tof(ushort h) {
    return __uint_as_float(((u32)h) << 16);
}

// ---------- Kernel 1: merged prep: bitpack adj (transposed) | split x | W tiles ----------
// blocks [0,65536): bitpack; [65536,67584): prepx; [67584,67712): prepw.
__global__ __launch_bounds__(256) void k_prep(const int* __restrict__ adj,
                                              const float* __restrict__ x,
                                              const float* __restrict__ W,
                                              u64* __restrict__ bmT,
                                              ushort* __restrict__ xh,
                                              ushort* __restrict__ xl,
                                              ushort* __restrict__ WTs) {
    int b = blockIdx.x;
    if (b < 65536) {
        int tid = b * 256 + threadIdx.x;
        int lane = threadIdx.x & 63;
        int v = adj[tid];
        u64 m = __ballot(v > 0);
        if (lane == 0) {
            int i = tid >> 12;           // row
            int j = tid & 4095;          // col of this wave's first lane
            bmT[(size_t)(j >> 6) * NN + i] = m;   // transposed: [jword][i]
        }
    } else if (b < 65536 + 2048) {
        int tid = (b - 65536) * 256 + threadIdx.x;     // NN*FIN/4 threads
        float4 v = *(const float4*)(x + (size_t)tid * 4);
        float fa[4] = {v.x, v.y, v.z, v.w};
        ushort4 hh, ll;
        ushort* hp = (ushort*)&hh; ushort* lp = (ushort*)&ll;
        #pragma unroll
        for (int k = 0; k < 4; ++k) {
            ushort hv = bf16rne(fa[k]);
            hp[k] = hv;
            lp[k] = bf16rne(fa[k] - bf16tof(hv));
        }
        *(ushort4*)(xh + (size_t)tid * 4) = hh;
        *(ushort4*)(xl + (size_t)tid * 4) = ll;
    } else {
        int gid = (b - 67584) * 256 + threadIdx.x;     // 32768 threads
        int d = gid & 63, kg = (gid >> 6) & 7, kt = (gid >> 9) & 7, h = gid >> 12;
        ushort hh[8], ll[8];
        #pragma unroll
        for (int e = 0; e < 8; ++e) {
            int f = kt * 64 + kg * 8 + e;
            float wv = W[((size_t)h * FIN + f) * DD + d];
            ushort hv = bf16rne(wv);
            hh[e] = hv;
            ll[e] = bf16rne(wv - bf16tof(hv));
        }
        *(uint4*)(WTs + ((size_t)((h * 2 + 0) * 8 + kt)) * 4096 + d * 64 + kg * 8) = *(uint4*)hh;
        *(uint4*)(WTs + ((size_t)((h * 2 + 1) * 8 + kt)) * 4096 + d * 64 + kg * 8) = *(uint4*)ll;
    }
}

// ---------- Kernel 2: MFMA projection, LDS-staged, 16 waves/block ----------
// grid (NN/64, HH), 1024 thr. Outputs WhbT linear tiles [h][it][d(64)][j(64)] bf16;
// s (f32) and tb16 (bf16), both pre-scaled by log2e.
__global__ __launch_bounds__(1024) void k_proj(const ushort* __restrict__ xh,
                                               const ushort* __restrict__ xl,
                                               const ushort* __restrict__ WTs,
                                               const float* __restrict__ a_src,
                                               const float* __restrict__ a_dst,
                                               ushort* __restrict__ WhbT,
                                               float* __restrict__ s,
                                               ushort* __restrict__ tb16) {
    __shared__ ushort P[16384];        // 4 bufs (Ah,Al,Bh,Bl) x 8KB, swizzled image
    __shared__ float SP[64][5], TP[64][5];
    int h = blockIdx.y, it = blockIdx.x;
    int i0 = it * 64;
    int tid = threadIdx.x;
    int w = tid >> 6, lane = tid & 63, lm = lane & 15, g = lane >> 4;
    int w_c = w & 3, w_i = w >> 2;
    f32x4 acc = {};
    int da = w_c * 16 + lm, ib = w_i * 16 + lm;
    for (int kt = 0; kt < 8; ++kt) {
        #pragma unroll
        for (int sub = 0; sub < 2; ++sub) {
            int buf = sub * 2 + (w >> 3);          // wave-uniform
            int y0 = (w & 7) * 64;                 // wave-uniform chunk base
            int y = y0 + lane;
            int r = y >> 3;
            int cc = (y & 7) ^ (r & 7);            // sigma: inverse-swizzle source
            const ushort* src;
            if (buf == 0)      src = WTs + ((size_t)((h * 2 + 0) * 8 + kt)) * 4096 + r * 64 + cc * 8;
            else if (buf == 1) src = WTs + ((size_t)((h * 2 + 1) * 8 + kt)) * 4096 + r * 64 + cc * 8;
            else if (buf == 2) src = xh + (size_t)(i0 + r) * FIN + kt * 64 + cc * 8;
            else               src = xl + (size_t)(i0 + r) * FIN + kt * 64 + cc * 8;
            GLOAD_LDS16(src, P + buf * 4096 + y0 * 8);
        }
        __syncthreads();
        #pragma unroll
        for (int ks = 0; ks < 2; ++ks) {
            u32 offA = ((u32)(da * 128 + ks * 64 + g * 16)) ^ ((u32)(da & 7) << 4);
            u32 offB = ((u32)(ib * 128 + ks * 64 + g * 16)) ^ ((u32)(ib & 7) << 4);
            short8 ah = *(const short8*)((const char*)P + offA);
            short8 al = *(const short8*)((const char*)P + 8192 + offA);
            short8 bh = *(const short8*)((const char*)P + 16384 + offB);
            short8 bl = *(const short8*)((const char*)P + 24576 + offB);
            acc = __builtin_amdgcn_mfma_f32_16x16x32_bf16(ah, bh, acc, 0, 0, 0);
            acc = __builtin_amdgcn_mfma_f32_16x16x32_bf16(al, bh, acc, 0, 0, 0);
            acc = __builtin_amdgcn_mfma_f32_16x16x32_bf16(ah, bl, acc, 0, 0, 0);
        }
        __syncthreads();
    }
    // epilogue: s,t partials + C tile. C[row=d=w_c*16+g*4+reg][col=i=w_i*16+lm]
    float4 as4 = *(const float4*)(a_src + h * DD + w_c * 16 + g * 4);
    float4 ad4 = *(const float4*)(a_dst + h * DD + w_c * 16 + g * 4);
    float sp = acc[0] * as4.x + acc[1] * as4.y + acc[2] * as4.z + acc[3] * as4.w;
    float tp = acc[0] * ad4.x + acc[1] * ad4.y + acc[2] * ad4.z + acc[3] * ad4.w;
    sp += __shfl_xor(sp, 16); sp += __shfl_xor(sp, 32);
    tp += __shfl_xor(tp, 16); tp += __shfl_xor(tp, 32);
    if (lane < 16) { SP[w_i * 16 + lm][w_c] = sp; TP[w_i * 16 + lm][w_c] = tp; }
    #pragma unroll
    for (int reg = 0; reg < 4; ++reg) {
        int d = w_c * 16 + g * 4 + reg;
        P[d * 64 + w_i * 16 + lm] = bf16rne(acc[reg]);
    }
    __syncthreads();
    const float LOG2E = 1.4426950408889634f;
    if (tid < 64) {
        int i = i0 + tid;
        s[h * NN + i] = (SP[tid][0] + SP[tid][1] + SP[tid][2] + SP[tid][3]) * LOG2E;
        tb16[h * NN + i] =
            bf16rne((TP[tid][0] + TP[tid][1] + TP[tid][2] + TP[tid][3]) * LOG2E);
    }
    ushort* tbase = WhbT + ((size_t)(h * 64 + it)) * 4096;
    if (tid < 512) {
        uint4 v = *(const uint4*)(P + tid * 8);
        *(uint4*)(tbase + tid * 8) = v;
    }
}

// ---------- Kernel 3: BARRIER-FREE fused aggregation: V global->reg, MFMA ----------
// grid (NN/64, HH), 512 thr = 4 j-groups x 2 waves x 32 rows; full j in-block.
// No per-tile barriers: each wave ping-pong prefetches its B-fragments from global
// (WhbT tiles are L1/L2-resident). LDS holds only t (bf16) + final combine area.
__global__ __launch_bounds__(512, 4) void k_agg(const ushort* __restrict__ WhbT,
                                                const float* __restrict__ s,
                                                const ushort* __restrict__ tb16,
                                                const u64* __restrict__ bmT,
                                                float* __restrict__ out) {
    __shared__ __attribute__((aligned(16))) char SM[75264];
    float*  PT  = (float*)SM;                   // 4 areas x 16KB = 64KB combine
    ushort* tls = (ushort*)(SM + 65536);        // 8KB bf16 t (log2-scaled)
    float*  PL  = (float*)(SM + 65536 + 8192);  // 4 x 64 l-partials
    int h = blockIdx.y;
    int i0 = blockIdx.x * 64;
    int tid = threadIdx.x;
    int w = tid >> 6, lane = tid & 63, r = lane & 31, hi = lane >> 5;
    int g = w >> 1, wr = w & 1;
    int irow = i0 + wr * 32 + r;
    float s_i = s[(size_t)h * NN + irow];       // log2-scaled
    // stage t once (whole head row, 8KB)
    *(uint4*)(tls + tid * 8) = *(const uint4*)(tb16 + (size_t)h * NN + tid * 8);
    __syncthreads();
    f32x16 acc0 = {}, acc1 = {};
    float lacc = 0.f;
    int jtbase = g * 16;
    const uint4* tbase = (const uint4*)(WhbT + ((size_t)(h * 64 + jtbase)) * 4096);
    int coff = r * 8 + hi;                      // 16B-chunk offset: d=r rows, hi half
    const ushort* tlsb = tls + (size_t)jtbase * 64;

#define LOADT(dst, bdst, kk)                                                         \
    {                                                                                \
        const uint4* tb_ = tbase + (kk) * 512;                                       \
        bdst = bmT[(size_t)(jtbase + (kk)) * NN + irow];                             \
        _Pragma("unroll")                                                            \
        for (int q = 0; q < 4; ++q) {                                                \
            dst[q]     = tb_[coff + q * 2];                                          \
            dst[4 + q] = tb_[256 + coff + q * 2];                                    \
        }                                                                            \
    }

#define COMPUTE(kk, vv, bits)                                                        \
    {                                                                                \
        _Pragma("unroll")                                                            \
        for (int jq = 0; jq < 4; ++jq) {                                             \
            short8 tv = *(const short8*)(tlsb + (kk) * 64 + jq * 16 + hi * 8);       \
            u32 msk = (u32)((bits) >> (jq * 16 + hi * 8)) & 0xffu;                   \
            float wv[8];                                                             \
            _Pragma("unroll")                                                        \
            for (int e = 0; e < 8; ++e) {                                            \
                float zz = s_i + bf16tof((ushort)tv[e]);                             \
                zz = fmaxf(zz, 0.2f * zz);                                           \
                float ex = EXP2F(zz);                                                \
                wv[e] = ((msk >> e) & 1u) ? ex : 0.f;                                \
                lacc += wv[e];                                                       \
            }                                                                        \
            union { u32 u[4]; short8 v8; } au;                                       \
            _Pragma("unroll")                                                        \
            for (int q = 0; q < 4; ++q) {                                            \
                __hip_bfloat162 b2 =                                                 \
                    __float22bfloat162_rn(make_float2(wv[2 * q], wv[2 * q + 1]));    \
                au.u[q] = *(u32*)&b2;                                                \
            }                                                                        \
            short8 b0 = *(short8*)&vv[jq];                                           \
            short8 b1 = *(short8*)&vv[4 + jq];                                       \
            __builtin_amdgcn_s_setprio(1);                                           \
            acc0 = __builtin_amdgcn_mfma_f32_32x32x16_bf16(au.v8, b0, acc0, 0, 0, 0);\
            acc1 = __builtin_amdgcn_mfma_f32_32x32x16_bf16(au.v8, b1, acc1, 0, 0, 0);\
            __builtin_amdgcn_s_setprio(0);                                           \
        }                                                                            \
    }

    uint4 vA[8], vB[8];
    u64 bitsA, bitsB;
    LOADT(vA, bitsA, 0);
    #pragma unroll 1
    for (int k = 0; k < 16; k += 2) {
        LOADT(vB, bitsB, k + 1);
        COMPUTE(k, vA, bitsA);
        if (k + 2 < 16) LOADT(vA, bitsA, k + 2);
        COMPUTE(k + 1, vB, bitsB);
    }
#undef LOADT
#undef COMPUTE

    // ---- in-block combine (the only barriers besides the t-stage one) ----
    lacc += __shfl_xor(lacc, 32);
    float* PTg = PT + g * 4096;                 // [64 rows][64 d] per group
    #pragma unroll
    for (int reg = 0; reg < 16; ++reg) {
        int rowl = (reg & 3) + 8 * (reg >> 2) + 4 * hi;
        PTg[(wr * 32 + rowl) * 64 + r]      = acc0[reg];
        PTg[(wr * 32 + rowl) * 64 + 32 + r] = acc1[reg];
    }
    if (lane < 32) PL[g * 64 + wr * 32 + lane] = lacc;
    __syncthreads();
    // epilogue: tid -> row (0..63), d0 = 8-float group
    int row = tid >> 3, d0 = (tid & 7) * 8;
    f32x4 a0 = {}, a1 = {};
    float l = 0.f;
    #pragma unroll
    for (int gg = 0; gg < 4; ++gg) {
        const float* Pp = PT + gg * 4096 + row * 64 + d0;
        a0 += *(const f32x4*)Pp;
        a1 += *(const f32x4*)(Pp + 4);
        l += PL[gg * 64 + row];
    }
    float inv = 1.f / l;
    float o[8];
    #pragma unroll
    for (int dd = 0; dd < 4; ++dd) {
        float u0 = a0[dd] * inv;
        float u1 = a1[dd] * inv;
        o[dd]     = u0 > 0.f ? u0 : __expf(u0) - 1.f;
        o[dd + 4] = u1 > 0.f ? u1 : __expf(u1) - 1.f;
    }
    float* ob = out + (size_t)(i0 + row) * (HH * DD) + h * DD + d0;
    *(float4*)ob       = make_float4(o[0], o[1], o[2], o[3]);
    *(float4*)(ob + 4) = make_float4(o[4], o[5], o[6], o[7]);
}

extern "C" void kernel_launch(void* const* d_in, const int* in_sizes, int n_in,
                              void* d_out, int out_size, void* d_ws, size_t ws_size,
                              hipStream_t stream) {
    const float* x     = (const float*)d_in[0];
    const int*   adj   = (const int*)d_in[1];
    const float* W     = (const float*)d_in[2];
    const float* a_src = (const float*)d_in[3];
    const float* a_dst = (const float*)d_in[4];
    float* out = (float*)d_out;

    char* ws = (char*)d_ws;
    const size_t MB = 1024 * 1024;
    ushort* WhbT = (ushort*)ws;                          // 4 MB, linear tiles
    u64*    bmT  = (u64*)(ws + 4 * MB);                  // 2 MB, transposed [jw][i]
    float*  s    = (float*)(ws + 6 * MB);                // 128 KB
    ushort* tb16 = (ushort*)(ws + 6 * MB + 128 * 1024);  // 64 KB
    ushort* xh   = (ushort*)(ws + 7 * MB);               // 4 MB
    ushort* xl   = (ushort*)(ws + 11 * MB);              // 4 MB
    ushort* WTs  = (ushort*)(ws + 15 * MB);              // 1 MB

    k_prep<<<dim3(65536 + 2048 + 128), dim3(256), 0, stream>>>(adj, x, W, bmT, xh, xl, WTs);
    k_proj<<<dim3(NN / 64, HH), dim3(1024), 0, stream>>>(xh, xl, WTs, a_src, a_dst, WhbT, s, tb16);
    k_agg<<<dim3(NN / 64, HH), dim3(512), 0, stream>>>(WhbT, s, tb16, bmT, out);
}

// Round 10
// 87.427 us; speedup vs baseline: 1.5822x; 1.5822x over previous
//
#include <hip/hip_runtime.h>
#include <hip/hip_bf16.h>
#include <math.h>

#define NN 4096
#define FIN 512
#define HH 8
#define DD 64

typedef unsigned long long u64;
typedef unsigned int u32;
typedef float f32x2 __attribute__((ext_vector_type(2)));
typedef float f32x4 __attribute__((ext_vector_type(4)));
typedef float f32x16 __attribute__((ext_vector_type(16)));
typedef short short8 __attribute__((ext_vector_type(8)));

#define GLOAD_LDS16(g, l)                                                              \
  __builtin_amdgcn_global_load_lds((const __attribute__((address_space(1))) u32*)(g),  \
                                   (__attribute__((address_space(3))) u32*)(l), 16, 0, 0)

#if __has_builtin(__builtin_amdgcn_exp2f)
#define EXP2F(x) __builtin_amdgcn_exp2f(x)
#else
#define EXP2F(x) exp2f(x)
#endif

__device__ inline ushort bf16rne(float f) {
    u32 u = __float_as_uint(f);
    u += 0x7FFFu + ((u >> 16) & 1u);
    return (ushort)(u >> 16);
}
__device__ inline float bf16tof(ushort h) {
    return __uint_as_float(((u32)h) << 16);
}

// ---------- Kernel 1: merged prep: bitpack adj (transposed) | split x | W tiles ----------
__global__ __launch_bounds__(256) void k_prep(const int* __restrict__ adj,
                                              const float* __restrict__ x,
                                              const float* __restrict__ W,
                                              u64* __restrict__ bmT,
                                              ushort* __restrict__ xh,
                                              ushort* __restrict__ xl,
                                              ushort* __restrict__ WTs) {
    int b = blockIdx.x;
    if (b < 65536) {
        int tid = b * 256 + threadIdx.x;
        int lane = threadIdx.x & 63;
        int v = adj[tid];
        u64 m = __ballot(v > 0);
        if (lane == 0) {
            int i = tid >> 12;           // row
            int j = tid & 4095;          // col of this wave's first lane
            bmT[(size_t)(j >> 6) * NN + i] = m;   // transposed: [jword][i]
        }
    } else if (b < 65536 + 2048) {
        int tid = (b - 65536) * 256 + threadIdx.x;     // NN*FIN/4 threads
        float4 v = *(const float4*)(x + (size_t)tid * 4);
        float fa[4] = {v.x, v.y, v.z, v.w};
        ushort4 hh, ll;
        ushort* hp = (ushort*)&hh; ushort* lp = (ushort*)&ll;
        #pragma unroll
        for (int k = 0; k < 4; ++k) {
            ushort hv = bf16rne(fa[k]);
            hp[k] = hv;
            lp[k] = bf16rne(fa[k] - bf16tof(hv));
        }
        *(ushort4*)(xh + (size_t)tid * 4) = hh;
        *(ushort4*)(xl + (size_t)tid * 4) = ll;
    } else {
        int gid = (b - 67584) * 256 + threadIdx.x;     // 32768 threads
        int d = gid & 63, kg = (gid >> 6) & 7, kt = (gid >> 9) & 7, h = gid >> 12;
        ushort hh[8], ll[8];
        #pragma unroll
        for (int e = 0; e < 8; ++e) {
            int f = kt * 64 + kg * 8 + e;
            float wv = W[((size_t)h * FIN + f) * DD + d];
            ushort hv = bf16rne(wv);
            hh[e] = hv;
            ll[e] = bf16rne(wv - bf16tof(hv));
        }
        *(uint4*)(WTs + ((size_t)((h * 2 + 0) * 8 + kt)) * 4096 + d * 64 + kg * 8) = *(uint4*)hh;
        *(uint4*)(WTs + ((size_t)((h * 2 + 1) * 8 + kt)) * 4096 + d * 64 + kg * 8) = *(uint4*)ll;
    }
}

// ---------- Kernel 2: MFMA projection, LDS-staged, 16 waves/block ----------
// grid (NN/64, HH), 1024 thr. Outputs WhbT linear tiles [h][it][d(64)][j(64)] bf16;
// s, t32 (both f32, pre-scaled by log2e).
__global__ __launch_bounds__(1024) void k_proj(const ushort* __restrict__ xh,
                                               const ushort* __restrict__ xl,
                                               const ushort* __restrict__ WTs,
                                               const float* __restrict__ a_src,
                                               const float* __restrict__ a_dst,
                                               ushort* __restrict__ WhbT,
                                               float* __restrict__ s,
                                               float* __restrict__ t32) {
    __shared__ ushort P[16384];        // 4 bufs (Ah,Al,Bh,Bl) x 8KB, swizzled image
    __shared__ float SP[64][5], TP[64][5];
    int h = blockIdx.y, it = blockIdx.x;
    int i0 = it * 64;
    int tid = threadIdx.x;
    int w = tid >> 6, lane = tid & 63, lm = lane & 15, g = lane >> 4;
    int w_c = w & 3, w_i = w >> 2;
    f32x4 acc = {};
    int da = w_c * 16 + lm, ib = w_i * 16 + lm;
    for (int kt = 0; kt < 8; ++kt) {
        #pragma unroll
        for (int sub = 0; sub < 2; ++sub) {
            int buf = sub * 2 + (w >> 3);          // wave-uniform
            int y0 = (w & 7) * 64;                 // wave-uniform chunk base
            int y = y0 + lane;
            int r = y >> 3;
            int cc = (y & 7) ^ (r & 7);            // sigma: inverse-swizzle source
            const ushort* src;
            if (buf == 0)      src = WTs + ((size_t)((h * 2 + 0) * 8 + kt)) * 4096 + r * 64 + cc * 8;
            else if (buf == 1) src = WTs + ((size_t)((h * 2 + 1) * 8 + kt)) * 4096 + r * 64 + cc * 8;
            else if (buf == 2) src = xh + (size_t)(i0 + r) * FIN + kt * 64 + cc * 8;
            else               src = xl + (size_t)(i0 + r) * FIN + kt * 64 + cc * 8;
            GLOAD_LDS16(src, P + buf * 4096 + y0 * 8);
        }
        __syncthreads();
        #pragma unroll
        for (int ks = 0; ks < 2; ++ks) {
            u32 offA = ((u32)(da * 128 + ks * 64 + g * 16)) ^ ((u32)(da & 7) << 4);
            u32 offB = ((u32)(ib * 128 + ks * 64 + g * 16)) ^ ((u32)(ib & 7) << 4);
            short8 ah = *(const short8*)((const char*)P + offA);
            short8 al = *(const short8*)((const char*)P + 8192 + offA);
            short8 bh = *(const short8*)((const char*)P + 16384 + offB);
            short8 bl = *(const short8*)((const char*)P + 24576 + offB);
            acc = __builtin_amdgcn_mfma_f32_16x16x32_bf16(ah, bh, acc, 0, 0, 0);
            acc = __builtin_amdgcn_mfma_f32_16x16x32_bf16(al, bh, acc, 0, 0, 0);
            acc = __builtin_amdgcn_mfma_f32_16x16x32_bf16(ah, bl, acc, 0, 0, 0);
        }
        __syncthreads();
    }
    // epilogue: s,t partials + C tile. C[row=d=w_c*16+g*4+reg][col=i=w_i*16+lm]
    float4 as4 = *(const float4*)(a_src + h * DD + w_c * 16 + g * 4);
    float4 ad4 = *(const float4*)(a_dst + h * DD + w_c * 16 + g * 4);
    float sp = acc[0] * as4.x + acc[1] * as4.y + acc[2] * as4.z + acc[3] * as4.w;
    float tp = acc[0] * ad4.x + acc[1] * ad4.y + acc[2] * ad4.z + acc[3] * ad4.w;
    sp += __shfl_xor(sp, 16); sp += __shfl_xor(sp, 32);
    tp += __shfl_xor(tp, 16); tp += __shfl_xor(tp, 32);
    if (lane < 16) { SP[w_i * 16 + lm][w_c] = sp; TP[w_i * 16 + lm][w_c] = tp; }
    #pragma unroll
    for (int reg = 0; reg < 4; ++reg) {
        int d = w_c * 16 + g * 4 + reg;
        P[d * 64 + w_i * 16 + lm] = bf16rne(acc[reg]);
    }
    __syncthreads();
    const float LOG2E = 1.4426950408889634f;
    if (tid < 64) {
        int i = i0 + tid;
        s[h * NN + i]   = (SP[tid][0] + SP[tid][1] + SP[tid][2] + SP[tid][3]) * LOG2E;
        t32[h * NN + i] = (TP[tid][0] + TP[tid][1] + TP[tid][2] + TP[tid][3]) * LOG2E;
    }
    ushort* tbase = WhbT + ((size_t)(h * 64 + it)) * 4096;
    if (tid < 512) {
        uint4 v = *(const uint4*)(P + tid * 8);
        *(uint4*)(tbase + tid * 8) = v;
    }
}

// ---------- Kernel 3: FUSED masked-softmax aggregation + ELU (round-7 structure) ----------
// grid (NN/64, HH), 512 thr = 4 j-groups x 2 waves x 32 rows; full j in-block.
// LDS-staged V (gload_lds, dbuf, 1 barrier/tile), f32 t in LDS, in-LDS combine.
__global__ __launch_bounds__(512, 4) void k_agg(const ushort* __restrict__ WhbT,
                                                const float* __restrict__ s,
                                                const float* __restrict__ t32,
                                                const u64* __restrict__ bmT,
                                                float* __restrict__ out) {
    __shared__ __attribute__((aligned(16))) char SM[81920];
    ushort* Vt  = (ushort*)SM;                 // 64KB: group g at g*16384, buf p at +p*8192
    float*  tls = (float*)(SM + 65536);        // 16KB f32 t (log2-scaled), whole j-range
    float*  PL  = (float*)(SM + 65536);        // reused for l-partials after loop (t dead)
    int h = blockIdx.y;
    int i0 = blockIdx.x * 64;
    int tid = threadIdx.x;
    int w = tid >> 6, lane = tid & 63, r = lane & 31, hi = lane >> 5;
    int g = w >> 1, wr = w & 1;
    int irow = i0 + wr * 32 + r;
    float s_i = s[(size_t)h * NN + irow];      // log2-scaled
    f32x2 s2; s2[0] = s_i; s2[1] = s_i;
    // stage t once (whole head row, 16KB f32)
    {
        const float4* src = (const float4*)(t32 + (size_t)h * NN) + tid * 2;
        ((float4*)tls)[tid * 2]     = src[0];
        ((float4*)tls)[tid * 2 + 1] = src[1];
    }
    f32x16 acc0 = {}, acc1 = {};
    float lacc = 0.f;
    int jtbase = g * 16;
    auto stage = [&](int p, int k) {
        const ushort* tb = WhbT + ((size_t)(h * 64 + jtbase + k)) * 4096;
        #pragma unroll
        for (int sub = 0; sub < 4; ++sub) {
            int y0 = wr * 256 + sub * 64;          // wave-uniform chunk base
            int y = y0 + lane;
            int sy = y ^ ((y >> 3) & 7);           // sigma source chunk
            GLOAD_LDS16(tb + sy * 8, (char*)Vt + g * 16384 + p * 8192 + y0 * 16);
        }
    };
    stage(0, 0);
    u64 bits = bmT[(size_t)jtbase * NN + irow];
    #pragma unroll 2
    for (int k = 0; k < 16; ++k) {
        __syncthreads();                 // buf[k&1] DMA complete; t staged; prev reads done
        if (k + 1 < 16) stage((k + 1) & 1, k + 1);
        u64 bnext = (k + 1 < 16) ? bmT[(size_t)(jtbase + k + 1) * NN + irow] : 0;
        int j0 = (jtbase + k) * 64;
        #pragma unroll
        for (int jq = 0; jq < 4; ++jq) {
            const float* tp = tls + j0 + jq * 16 + hi * 8;
            float ta[8];
            *(f32x4*)&ta[0] = *(const f32x4*)tp;
            *(f32x4*)&ta[4] = *(const f32x4*)(tp + 4);
            u32 msk = (u32)(bits >> (jq * 16 + hi * 8)) & 0xffu;
            union { u32 u[4]; short8 v8; } au;
            #pragma unroll
            for (int q = 0; q < 4; ++q) {
                f32x2 t2; t2[0] = ta[2 * q]; t2[1] = ta[2 * q + 1];
                f32x2 z = s2 + t2;               // v_pk_add_f32 hopeful
                f32x2 zl = z * 0.2f;             // v_pk_mul_f32 hopeful
                float z0 = fmaxf(z[0], zl[0]);
                float z1 = fmaxf(z[1], zl[1]);
                float e0 = EXP2F(z0), e1 = EXP2F(z1);
                e0 = ((msk >> (2 * q)) & 1u) ? e0 : 0.f;
                e1 = ((msk >> (2 * q + 1)) & 1u) ? e1 : 0.f;
                lacc += e0 + e1;
                __hip_bfloat162 b2 = __float22bfloat162_rn(make_float2(e0, e1));
                au.u[q] = *(u32*)&b2;
            }
            u32 o0 = (u32)(g * 16384 + (k & 1) * 8192) + (u32)(r * 128) +
                     (((u32)(jq * 32 + hi * 16)) ^ ((u32)(r & 7) << 4));
            short8 b0 = *(const short8*)((const char*)Vt + o0);
            short8 b1 = *(const short8*)((const char*)Vt + o0 + 4096);
            __builtin_amdgcn_s_setprio(1);
            acc0 = __builtin_amdgcn_mfma_f32_32x32x16_bf16(au.v8, b0, acc0, 0, 0, 0);
            acc1 = __builtin_amdgcn_mfma_f32_32x32x16_bf16(au.v8, b1, acc1, 0, 0, 0);
            __builtin_amdgcn_s_setprio(0);
        }
        bits = bnext;
    }
    // ---- in-block combine ----
    lacc += __shfl_xor(lacc, 32);
    __syncthreads();                     // all waves done reading Vt & tls
    float* PTg = (float*)(SM + g * 16384);   // [64 rows][64 d] per group (over Vt)
    #pragma unroll
    for (int reg = 0; reg < 16; ++reg) {
        int rowl = (reg & 3) + 8 * (reg >> 2) + 4 * hi;
        PTg[(wr * 32 + rowl) * 64 + r]      = acc0[reg];
        PTg[(wr * 32 + rowl) * 64 + 32 + r] = acc1[reg];
    }
    if (lane < 32) PL[g * 64 + wr * 32 + lane] = lacc;
    __syncthreads();
    // epilogue: tid -> row (0..63), d0 = 8-float group
    int row = tid >> 3, d0 = (tid & 7) * 8;
    f32x4 a0 = {}, a1 = {};
    float l = 0.f;
    #pragma unroll
    for (int gg = 0; gg < 4; ++gg) {
        const float* Pp = (const float*)(SM + gg * 16384) + row * 64 + d0;
        a0 += *(const f32x4*)Pp;
        a1 += *(const f32x4*)(Pp + 4);
        l += PL[gg * 64 + row];
    }
    float inv = 1.f / l;
    float o[8];
    #pragma unroll
    for (int dd = 0; dd < 4; ++dd) {
        float u0 = a0[dd] * inv;
        float u1 = a1[dd] * inv;
        o[dd]     = u0 > 0.f ? u0 : __expf(u0) - 1.f;
        o[dd + 4] = u1 > 0.f ? u1 : __expf(u1) - 1.f;
    }
    float* ob = out + (size_t)(i0 + row) * (HH * DD) + h * DD + d0;
    *(float4*)ob       = make_float4(o[0], o[1], o[2], o[3]);
    *(float4*)(ob + 4) = make_float4(o[4], o[5], o[6], o[7]);
}

extern "C" void kernel_launch(void* const* d_in, const int* in_sizes, int n_in,
                              void* d_out, int out_size, void* d_ws, size_t ws_size,
                              hipStream_t stream) {
    const float* x     = (const float*)d_in[0];
    const int*   adj   = (const int*)d_in[1];
    const float* W     = (const float*)d_in[2];
    const float* a_src = (const float*)d_in[3];
    const float* a_dst = (const float*)d_in[4];
    float* out = (float*)d_out;

    char* ws = (char*)d_ws;
    const size_t MB = 1024 * 1024;
    ushort* WhbT = (ushort*)ws;                          // 4 MB, linear tiles
    u64*    bmT  = (u64*)(ws + 4 * MB);                  // 2 MB, transposed [jw][i]
    float*  s    = (float*)(ws + 6 * MB);                // 128 KB
    float*  t32  = (float*)(ws + 6 * MB + 128 * 1024);   // 128 KB
    ushort* xh   = (ushort*)(ws + 7 * MB);               // 4 MB
    ushort* xl   = (ushort*)(ws + 11 * MB);              // 4 MB
    ushort* WTs  = (ushort*)(ws + 15 * MB);              // 1 MB

    k_prep<<<dim3(65536 + 2048 + 128), dim3(256), 0, stream>>>(adj, x, W, bmT, xh, xl, WTs);
    k_proj<<<dim3(NN / 64, HH), dim3(1024), 0, stream>>>(xh, xl, WTs, a_src, a_dst, WhbT, s, t32);
    k_agg<<<dim3(NN / 64, HH), dim3(512), 0, stream>>>(WhbT, s, t32, bmT, out);
}